// Round 11
// baseline (847.441 us; speedup 1.0000x reference)
//
#include <hip/hip_runtime.h>
#include <math.h>

#define VOL   128
#define V2    (VOL*VOL)
#define V3    (VOL*VOL*VOL)
#define NPTS  262144
#define LATD  16
#define BATCH 8
#define FACTORF 64.0f

// Round-to-nearest-even float -> bf16 -> float (ml_dtypes / XLA bf16 RNE)
__device__ __forceinline__ float bf16r(float x) {
    unsigned u = __float_as_uint(x);
    u = (u + 0x7fffu + ((u >> 16) & 1u)) & 0xffff0000u;
    return __uint_as_float(u);
}

// SIREN MLP, faithful per-op bf16 (XLA / ml_dtypes semantics):
// dot: f32 accumulate, round ONCE to bf16 (np: f32 matmul + astype(bf16));
// each elementwise op (+bias, *30, sin, residual add) rounds its result.
__global__ void mlp_kernel(const float* __restrict__ x,
                           const float* __restrict__ W0,
                           const float* __restrict__ b0,
                           const float* __restrict__ Wh,
                           const float* __restrict__ bh,
                           float* __restrict__ hout) {
    int b = threadIdx.x;
    if (b >= BATCH) return;
    float xb[LATD];
    #pragma unroll
    for (int i = 0; i < LATD; ++i) xb[i] = bf16r(x[b*LATD + i]);
    float h[8];
    #pragma unroll
    for (int j = 0; j < 8; ++j) {
        float acc = 0.f;
        #pragma unroll
        for (int i = 0; i < LATD; ++i) acc += xb[i] * bf16r(W0[i*8 + j]);
        float t = bf16r(acc);                  // matmul result -> bf16
        t = bf16r(t + bf16r(b0[j]));           // + bias (bf16 op)
        t = bf16r(30.0f * t);                  // 30 * (...) (bf16 op)
        h[j] = bf16r(sinf(t));                 // sin: f32 compute, bf16 round
    }
    for (int l = 0; l < 4; ++l) {
        float nh[8];
        #pragma unroll
        for (int j = 0; j < 8; ++j) {
            float acc = 0.f;
            #pragma unroll
            for (int r = 0; r < 8; ++r) acc += h[r] * bf16r(Wh[(l*8 + r)*8 + j]);
            float t = bf16r(acc);
            t = bf16r(t + bf16r(bh[l*8 + j]));
            float s = bf16r(sinf(t));
            nh[j] = bf16r(h[j] + s);           // residual add (bf16 op)
        }
        #pragma unroll
        for (int j = 0; j < 8; ++j) h[j] = nh[j];
    }
    #pragma unroll
    for (int j = 0; j < 8; ++j) hout[b*8 + j] = h[j];  // bf16 -> f32 exact
}

// One thread per point: fused final matmul + trilinear scatter for all 8 batches.
// WRAP (&127) == np.add.at semantics: proven by the MLP-independent 0.394531
// plateau under drop (= ref's wrapped contribution at z/y/x=127 voxels).
__global__ __launch_bounds__(256) void scatter_kernel(
    const float* __restrict__ Wf, const float* __restrict__ bfv_g,
    const float* __restrict__ rv, const int* __restrict__ inds,
    const float* __restrict__ hbuf, float* __restrict__ out)
{
    __shared__ float hs[BATCH*8];
    if (threadIdx.x < BATCH*8) hs[threadIdx.x] = hbuf[threadIdx.x];
    __syncthreads();

    int n = blockIdx.x * blockDim.x + threadIdx.x;
    if (n >= NPTS) return;

    int iz = inds[n*3 + 0], iy = inds[n*3 + 1], ix = inds[n*3 + 2];
    float cnx = ((float)ix - FACTORF) / FACTORF;
    float cny = ((float)iy - FACTORF) / FACTORF;
    float cnz = ((float)iz - FACTORF) / FACTORF;
    float val0 = rv[n];
    float4 bfv = ((const float4*)bfv_g)[n];

    float4 wf[8];
    #pragma unroll
    for (int r = 0; r < 8; ++r)
        wf[r] = ((const float4*)(Wf + (size_t)r * 4 * NPTS))[n];

    static const int offs[8][3] = {{0,0,0},{1,0,0},{0,1,0},{0,0,1},
                                   {0,1,1},{1,0,1},{1,1,0},{1,1,1}};

    #pragma unroll
    for (int b = 0; b < BATCH; ++b) {
        float o0 = bfv.x, o1 = bfv.y, o2 = bfv.z, o3 = bfv.w;
        #pragma unroll
        for (int r = 0; r < 8; ++r) {
            float hv = hs[b*8 + r];
            o0 = fmaf(hv, wf[r].x, o0);
            o1 = fmaf(hv, wf[r].y, o1);
            o2 = fmaf(hv, wf[r].z, o2);
            o3 = fmaf(hv, wf[r].w, o3);
        }
        float cx = FACTORF * (cnx + o0) + FACTORF;
        float cy = FACTORF * (cny + o1) + FACTORF;
        float cz = FACTORF * (cnz + o2) + FACTORF;
        float val = val0 + o3;

        float fxf = floorf(cx), fyf = floorf(cy), fzf = floorf(cz);
        int bx = (int)fxf, by = (int)fyf, bz = (int)fzf;
        float fx = cx - fxf, fy = cy - fyf, fz = cz - fzf;
        float gx = 1.f - fx, gy = 1.f - fy, gz = 1.f - fz;

        float w[8] = {gx*gy*gz, fx*gy*gz, gx*fy*gz, gx*gy*fz,
                      gx*fy*fz, fx*gy*fz, fx*fy*gz, fx*fy*fz};

        float* ob = out + (size_t)b * V3;
        #pragma unroll
        for (int o = 0; o < 8; ++o) {
            int X = (bx + offs[o][0]) & (VOL-1);
            int Y = (by + offs[o][1]) & (VOL-1);
            int Z = (bz + offs[o][2]) & (VOL-1);
            atomicAdd(ob + (size_t)Z*V2 + Y*VOL + X, val * w[o]);
        }
    }
}

extern "C" void kernel_launch(void* const* d_in, const int* in_sizes, int n_in,
                              void* d_out, int out_size, void* d_ws, size_t ws_size,
                              hipStream_t stream) {
    const float* x    = (const float*)d_in[0];
    const float* W0   = (const float*)d_in[1];
    const float* b0   = (const float*)d_in[2];
    const float* Wh   = (const float*)d_in[3];
    const float* bh   = (const float*)d_in[4];
    const float* Wf   = (const float*)d_in[5];
    const float* bf   = (const float*)d_in[6];
    const float* rv   = (const float*)d_in[7];
    const int*   inds = (const int*)d_in[8];
    float* out  = (float*)d_out;
    float* hbuf = (float*)d_ws;

    hipMemsetAsync(d_out, 0, (size_t)out_size * sizeof(float), stream);
    mlp_kernel<<<1, 64, 0, stream>>>(x, W0, b0, Wh, bh, hbuf);
    scatter_kernel<<<NPTS/256, 256, 0, stream>>>(Wf, bf, rv, inds, hbuf, out);
}